// Round 5
// baseline (737.736 us; speedup 1.0000x reference)
//
#include <hip/hip_runtime.h>

#define D 256  // D_IN == D_OUT == 256

typedef __attribute__((ext_vector_type(8))) short bf16x8;  // 8 bf16 in 4 VGPRs
typedef __attribute__((ext_vector_type(4))) float f32x4;

__device__ inline ushort f2bf_rne(float f) {  // fp32 -> bf16, round-to-nearest-even
    uint u = __builtin_bit_cast(uint, f);
    return (ushort)((u + 0x7FFFu + ((u >> 16) & 1u)) >> 16);
}

// ===========================================================================
// W transpose + bf16 convert: wt[n][k] = bf16(W[k][n])
// ===========================================================================
__global__ __launch_bounds__(256) void conv_wt(const float* __restrict__ w,
                                               ushort* __restrict__ wt) {
    const int idx = blockIdx.x * 256 + threadIdx.x;
    const int n = idx >> 8, k = idx & 255;
    wt[n * 256 + k] = f2bf_rne(w[k * 256 + n]);
}

// ===========================================================================
// support = bf16(x @ W) via MFMA 16x16x32 bf16.  (verified: absmax 2.0 ok)
// ===========================================================================
__global__ __launch_bounds__(256) void gemm_mfma(const float* __restrict__ x,
                                                 const ushort* __restrict__ wt,
                                                 ushort* __restrict__ sup,
                                                 int N) {
    __shared__ ushort As[64 * 256];  // 32 KB, XOR-swizzled
    const int tid = threadIdx.x;
    const int wv  = tid >> 6;
    const int ln  = tid & 63;
    const int row0 = blockIdx.x * 64;

    for (int i = tid; i < 64 * 64; i += 256) {
        const int r = i >> 6, c = i & 63;
        int gr = row0 + r;
        if (gr >= N) gr = N - 1;
        const float4 xv = *(const float4*)(x + (size_t)gr * D + c * 4);
        ushort4 b;
        b.x = f2bf_rne(xv.x); b.y = f2bf_rne(xv.y);
        b.z = f2bf_rne(xv.z); b.w = f2bf_rne(xv.w);
        const int byte = (r * 512 + c * 8) ^ ((r & 7) << 4);
        *(ushort4*)((char*)As + byte) = b;
    }
    __syncthreads();

    f32x4 acc[16];
#pragma unroll
    for (int n = 0; n < 16; ++n) acc[n] = (f32x4){0.f, 0.f, 0.f, 0.f};

    const int arow = wv * 16 + (ln & 15);
    const int ksub = (ln >> 4) * 16;
    const ushort* wbase = wt + (ln & 15) * 256;

#pragma unroll
    for (int kk = 0; kk < 8; ++kk) {
        const int abyte = (arow * 512 + kk * 64 + ksub) ^ ((arow & 7) << 4);
        const bf16x8 af = *(const bf16x8*)((const char*)As + abyte);
        const ushort* wp = wbase + kk * 32 + (ln >> 4) * 8;
#pragma unroll
        for (int n = 0; n < 16; ++n) {
            const bf16x8 bf = *(const bf16x8*)(wp + n * 16 * 256);
            acc[n] = __builtin_amdgcn_mfma_f32_16x16x32_bf16(af, bf, acc[n], 0, 0, 0);
        }
    }

    const int crow = row0 + wv * 16 + (ln >> 4) * 4;
    const int ccol = ln & 15;
#pragma unroll
    for (int n = 0; n < 16; ++n) {
#pragma unroll
        for (int reg = 0; reg < 4; ++reg) {
            const int r = crow + reg;
            if (r < N) sup[(size_t)r * D + n * 16 + ccol] = f2bf_rne(acc[n][reg]);
        }
    }
}

// ===========================================================================
// CSR build
// ===========================================================================
__global__ __launch_bounds__(256) void zero_ints(int* __restrict__ p, int n) {
    const int i = blockIdx.x * 256 + threadIdx.x;
    if (i < n) p[i] = 0;
}

__global__ __launch_bounds__(256) void hist_rows(const int* __restrict__ edge_row,
                                                 int* __restrict__ cnt, int E) {
    const int i = (blockIdx.x * 256 + threadIdx.x) * 4;
    if (i + 3 < E) {
        const int4 r = *(const int4*)(edge_row + i);
        atomicAdd(&cnt[r.x], 1);  // no return value used -> fire-and-forget
        atomicAdd(&cnt[r.y], 1);
        atomicAdd(&cnt[r.z], 1);
        atomicAdd(&cnt[r.w], 1);
    } else {
        for (int e = i; e < E; ++e) atomicAdd(&cnt[edge_row[e]], 1);
    }
}

__global__ __launch_bounds__(256) void scan_local(const int* __restrict__ cnt,
                                                  int* __restrict__ row_start,
                                                  int* __restrict__ partial, int N) {
    __shared__ int tmp[256];
    const int tid = threadIdx.x;
    const int i   = blockIdx.x * 256 + tid;
    const int v   = (i < N) ? cnt[i] : 0;
    tmp[tid] = v;
    __syncthreads();
#pragma unroll
    for (int off = 1; off < 256; off <<= 1) {
        const int t = (tid >= off) ? tmp[tid - off] : 0;
        __syncthreads();
        tmp[tid] += t;
        __syncthreads();
    }
    if (i < N) row_start[i] = tmp[tid] - v;
    if (tid == 255) partial[blockIdx.x] = tmp[255];
}

__global__ __launch_bounds__(512) void scan_partials(int* __restrict__ partial, int nblk) {
    __shared__ int tmp[512];
    const int tid = threadIdx.x;
    const int v   = (tid < nblk) ? partial[tid] : 0;
    tmp[tid] = v;
    __syncthreads();
#pragma unroll
    for (int off = 1; off < 512; off <<= 1) {
        const int t = (tid >= off) ? tmp[tid - off] : 0;
        __syncthreads();
        tmp[tid] += t;
        __syncthreads();
    }
    if (tid < nblk) partial[tid] = tmp[tid] - v;
}

__global__ __launch_bounds__(256) void scan_finalize(int* __restrict__ row_start,
                                                     int* __restrict__ cursor,
                                                     const int* __restrict__ partial,
                                                     int N, int E) {
    const int i = blockIdx.x * 256 + threadIdx.x;
    if (i < N) {
        const int s = row_start[i] + partial[blockIdx.x];
        row_start[i] = s;
        cursor[i]    = s;
    }
    if (blockIdx.x == 0 && threadIdx.x == 0) row_start[N] = E;
}

// packed (col, val): low 32 = col, high 32 = val bits. ONE 8B scatter per edge.
__device__ inline long long pack_cv(int c, float v) {
    return (long long)(((unsigned long long)__builtin_bit_cast(uint, v) << 32) |
                       (uint)c);
}

// 1 edge/thread: the atomic->store dependent chain is ~300-600 cy; 3.2M
// threads give the scheduler maximal latency hiding. Plain (cached) store:
// L2 write-back merges the 8 epair entries per 64B line and keeps epair
// resident for accumulate.
__global__ __launch_bounds__(256) void fill_csr(const int* __restrict__ edge_row,
                                                const int* __restrict__ edge_col,
                                                const float* __restrict__ edge_val,
                                                int* __restrict__ cursor,
                                                long long* __restrict__ epair, int E) {
    const int e = blockIdx.x * 256 + threadIdx.x;
    if (e >= E) return;
    const int pos = atomicAdd(&cursor[edge_row[e]], 1);
    epair[pos] = pack_cv(edge_col[e], edge_val[e]);
}

// ===========================================================================
// accumulate: one wave per row; 8 gathers in flight; bias folded in.
// ===========================================================================
__global__ __launch_bounds__(256) void accumulate(const ushort* __restrict__ sup,
                                                  const int* __restrict__ row_start,
                                                  const long long* __restrict__ epair,
                                                  const float* __restrict__ bias,
                                                  float* __restrict__ out, int N) {
    const int row = blockIdx.x * 4 + (threadIdx.x >> 6);
    if (row >= N) return;
    const int lane = threadIdx.x & 63;
    const int lofs = lane * 4;  // ushort offset within a sup row

    const int s = row_start[row];
    const int e = row_start[row + 1];

    f32x4 a[8];
    a[0] = *(const f32x4*)(bias + lofs);
#pragma unroll
    for (int q = 1; q < 8; ++q) a[q] = (f32x4){0.f, 0.f, 0.f, 0.f};

    for (int base = s; base < e; base += 64) {
        const int idx = base + lane;
        long long pk = 0;
        if (idx < e) pk = __builtin_nontemporal_load(epair + idx);
        const int   c = (int)(uint)pk;
        const float v = __builtin_bit_cast(float, (uint)((unsigned long long)pk >> 32));
        const int n = min(64, e - base);
        int j = 0;
        for (; j + 7 < n; j += 8) {
            int   cq[8];
            float vq[8];
            uint2 uq[8];
#pragma unroll
            for (int q = 0; q < 8; ++q) {
                cq[q] = __shfl(c, j + q);
                vq[q] = __shfl(v, j + q);
            }
#pragma unroll
            for (int q = 0; q < 8; ++q)
                uq[q] = *(const uint2*)(sup + ((uint)cq[q] << 8) + lofs);
#pragma unroll
            for (int q = 0; q < 8; ++q) {
                const float f0 = __builtin_bit_cast(float, uq[q].x << 16);
                const float f1 = __builtin_bit_cast(float, uq[q].x & 0xFFFF0000u);
                const float f2 = __builtin_bit_cast(float, uq[q].y << 16);
                const float f3 = __builtin_bit_cast(float, uq[q].y & 0xFFFF0000u);
                a[q][0] = fmaf(vq[q], f0, a[q][0]);
                a[q][1] = fmaf(vq[q], f1, a[q][1]);
                a[q][2] = fmaf(vq[q], f2, a[q][2]);
                a[q][3] = fmaf(vq[q], f3, a[q][3]);
            }
        }
        for (; j < n; ++j) {
            const int   c0 = __shfl(c, j);
            const float v0 = __shfl(v, j);
            const uint2 u  = *(const uint2*)(sup + ((uint)c0 << 8) + lofs);
            const float f0 = __builtin_bit_cast(float, u.x << 16);
            const float f1 = __builtin_bit_cast(float, u.x & 0xFFFF0000u);
            const float f2 = __builtin_bit_cast(float, u.y << 16);
            const float f3 = __builtin_bit_cast(float, u.y & 0xFFFF0000u);
            a[0][0] = fmaf(v0, f0, a[0][0]);
            a[0][1] = fmaf(v0, f1, a[0][1]);
            a[0][2] = fmaf(v0, f2, a[0][2]);
            a[0][3] = fmaf(v0, f3, a[0][3]);
        }
    }
#pragma unroll
    for (int q = 1; q < 8; ++q) {
        a[0][0] += a[q][0]; a[0][1] += a[q][1];
        a[0][2] += a[q][2]; a[0][3] += a[q][3];
    }
    __builtin_nontemporal_store(a[0], (f32x4*)(out + (size_t)row * D + lofs));
}

// ===========================================================================
extern "C" void kernel_launch(void* const* d_in, const int* in_sizes, int n_in,
                              void* d_out, int out_size, void* d_ws, size_t ws_size,
                              hipStream_t stream) {
    const float* x        = (const float*)d_in[0];
    const float* edge_val = (const float*)d_in[1];
    const float* weight   = (const float*)d_in[2];
    const float* bias     = (const float*)d_in[3];
    const int*   edge_row = (const int*)d_in[4];
    const int*   edge_col = (const int*)d_in[5];
    float*       out      = (float*)d_out;

    const int N = in_sizes[0] / D;   // 100000
    const int E = in_sizes[1];       // 3200000

    char* ws = (char*)d_ws;
    size_t off = 0;
    auto carve = [&](size_t bytes) -> char* {
        char* p = ws + off;
        off = (off + bytes + 255) & ~(size_t)255;
        return p;
    };

    const int nblk = (N + 255) / 256;  // 391

    ushort*    sup       = (ushort*)carve((size_t)N * D * sizeof(ushort));  // 51.2 MB
    ushort*    wt        = (ushort*)carve((size_t)D * D * sizeof(ushort));  // 128 KB
    int*       row_start = (int*)carve((size_t)(N + 1) * sizeof(int));
    int*       cursor    = (int*)carve((size_t)N * sizeof(int));
    long long* epair     = (long long*)carve((size_t)E * sizeof(long long)); // 25.6 MB
    int*       partial   = (int*)carve((size_t)nblk * sizeof(int));

    // 1) W -> wt (bf16 transposed), support = bf16(x @ W)
    conv_wt<<<(D * D) / 256, 256, 0, stream>>>(weight, wt);
    gemm_mfma<<<(N + 63) / 64, 256, 0, stream>>>(x, wt, sup, N);

    // 2) CSR build
    zero_ints<<<nblk, 256, 0, stream>>>(cursor, N);
    hist_rows<<<(E / 4 + 255) / 256, 256, 0, stream>>>(edge_row, cursor, E);
    scan_local<<<nblk, 256, 0, stream>>>(cursor, row_start, partial, N);
    scan_partials<<<1, 512, 0, stream>>>(partial, nblk);
    scan_finalize<<<nblk, 256, 0, stream>>>(row_start, cursor, partial, N, E);
    fill_csr<<<(E + 255) / 256, 256, 0, stream>>>(edge_row, edge_col, edge_val,
                                                  cursor, epair, E);

    // 3) gather-accumulate (bias folded in)
    accumulate<<<(N + 3) / 4, 256, 0, stream>>>(sup, row_start, epair, bias, out, N);
}

// Round 6
// 573.761 us; speedup vs baseline: 1.2858x; 1.2858x over previous
//
#include <hip/hip_runtime.h>

#define D 256          // D_IN == D_OUT == 256
#define BSHIFT 7       // 128 rows per coarse bucket
#define BROWS 128
#define CHUNK 8192     // edges per bucket_scatter block

typedef __attribute__((ext_vector_type(8))) short bf16x8;  // 8 bf16 in 4 VGPRs
typedef __attribute__((ext_vector_type(4))) float f32x4;

__device__ inline ushort f2bf_rne(float f) {  // fp32 -> bf16, round-to-nearest-even
    uint u = __builtin_bit_cast(uint, f);
    return (ushort)((u + 0x7FFFu + ((u >> 16) & 1u)) >> 16);
}

// ===========================================================================
// W transpose + bf16 convert: wt[n][k] = bf16(W[k][n])
// ===========================================================================
__global__ __launch_bounds__(256) void conv_wt(const float* __restrict__ w,
                                               ushort* __restrict__ wt) {
    const int idx = blockIdx.x * 256 + threadIdx.x;
    const int n = idx >> 8, k = idx & 255;
    wt[n * 256 + k] = f2bf_rne(w[k * 256 + n]);
}

// ===========================================================================
// support = bf16(x @ W) via MFMA 16x16x32 bf16.  (verified: absmax 2.0 ok)
// ===========================================================================
__global__ __launch_bounds__(256) void gemm_mfma(const float* __restrict__ x,
                                                 const ushort* __restrict__ wt,
                                                 ushort* __restrict__ sup,
                                                 int N) {
    __shared__ ushort As[64 * 256];  // 32 KB, XOR-swizzled
    const int tid = threadIdx.x;
    const int wv  = tid >> 6;
    const int ln  = tid & 63;
    const int row0 = blockIdx.x * 64;

    for (int i = tid; i < 64 * 64; i += 256) {
        const int r = i >> 6, c = i & 63;
        int gr = row0 + r;
        if (gr >= N) gr = N - 1;
        const float4 xv = *(const float4*)(x + (size_t)gr * D + c * 4);
        ushort4 b;
        b.x = f2bf_rne(xv.x); b.y = f2bf_rne(xv.y);
        b.z = f2bf_rne(xv.z); b.w = f2bf_rne(xv.w);
        const int byte = (r * 512 + c * 8) ^ ((r & 7) << 4);
        *(ushort4*)((char*)As + byte) = b;
    }
    __syncthreads();

    f32x4 acc[16];
#pragma unroll
    for (int n = 0; n < 16; ++n) acc[n] = (f32x4){0.f, 0.f, 0.f, 0.f};

    const int arow = wv * 16 + (ln & 15);
    const int ksub = (ln >> 4) * 16;
    const ushort* wbase = wt + (ln & 15) * 256;

#pragma unroll
    for (int kk = 0; kk < 8; ++kk) {
        const int abyte = (arow * 512 + kk * 64 + ksub) ^ ((arow & 7) << 4);
        const bf16x8 af = *(const bf16x8*)((const char*)As + abyte);
        const ushort* wp = wbase + kk * 32 + (ln >> 4) * 8;
#pragma unroll
        for (int n = 0; n < 16; ++n) {
            const bf16x8 bf = *(const bf16x8*)(wp + n * 16 * 256);
            acc[n] = __builtin_amdgcn_mfma_f32_16x16x32_bf16(af, bf, acc[n], 0, 0, 0);
        }
    }

    const int crow = row0 + wv * 16 + (ln >> 4) * 4;
    const int ccol = ln & 15;
#pragma unroll
    for (int n = 0; n < 16; ++n) {
#pragma unroll
        for (int reg = 0; reg < 4; ++reg) {
            const int r = crow + reg;
            if (r < N) sup[(size_t)r * D + n * 16 + ccol] = f2bf_rne(acc[n][reg]);
        }
    }
}

// ===========================================================================
// Fine histogram + scan -> row_start
// ===========================================================================
__global__ __launch_bounds__(256) void zero_ints(int* __restrict__ p, int n) {
    const int i = blockIdx.x * 256 + threadIdx.x;
    if (i < n) p[i] = 0;
}

__global__ __launch_bounds__(256) void hist_rows(const int* __restrict__ edge_row,
                                                 int* __restrict__ cnt, int E) {
    const int i = (blockIdx.x * 256 + threadIdx.x) * 4;
    if (i + 3 < E) {
        const int4 r = *(const int4*)(edge_row + i);
        atomicAdd(&cnt[r.x], 1);  // fire-and-forget
        atomicAdd(&cnt[r.y], 1);
        atomicAdd(&cnt[r.z], 1);
        atomicAdd(&cnt[r.w], 1);
    } else {
        for (int e = i; e < E; ++e) atomicAdd(&cnt[edge_row[e]], 1);
    }
}

__global__ __launch_bounds__(256) void scan_local(const int* __restrict__ cnt,
                                                  int* __restrict__ row_start,
                                                  int* __restrict__ partial, int N) {
    __shared__ int tmp[256];
    const int tid = threadIdx.x;
    const int i   = blockIdx.x * 256 + tid;
    const int v   = (i < N) ? cnt[i] : 0;
    tmp[tid] = v;
    __syncthreads();
#pragma unroll
    for (int off = 1; off < 256; off <<= 1) {
        const int t = (tid >= off) ? tmp[tid - off] : 0;
        __syncthreads();
        tmp[tid] += t;
        __syncthreads();
    }
    if (i < N) row_start[i] = tmp[tid] - v;
    if (tid == 255) partial[blockIdx.x] = tmp[255];
}

__global__ __launch_bounds__(512) void scan_partials(int* __restrict__ partial, int nblk) {
    __shared__ int tmp[512];
    const int tid = threadIdx.x;
    const int v   = (tid < nblk) ? partial[tid] : 0;
    tmp[tid] = v;
    __syncthreads();
#pragma unroll
    for (int off = 1; off < 512; off <<= 1) {
        const int t = (tid >= off) ? tmp[tid - off] : 0;
        __syncthreads();
        tmp[tid] += t;
        __syncthreads();
    }
    if (tid < nblk) partial[tid] = tmp[tid] - v;
}

__global__ __launch_bounds__(256) void scan_finalize(int* __restrict__ row_start,
                                                     const int* __restrict__ partial,
                                                     int N, int E) {
    const int i = blockIdx.x * 256 + threadIdx.x;
    if (i < N) row_start[i] += partial[blockIdx.x];
    if (blockIdx.x == 0 && threadIdx.x == 0) row_start[N] = E;
}

// bucket_cursor[b] = row_start[min(b*BROWS, N)]
__global__ __launch_bounds__(256) void init_bcursor(const int* __restrict__ row_start,
                                                    int* __restrict__ bucket_cursor,
                                                    int N, int NB) {
    const int b = blockIdx.x * 256 + threadIdx.x;
    if (b < NB) {
        int r = b << BSHIFT;
        if (r > N) r = N;
        bucket_cursor[b] = row_start[r];
    }
}

// ===========================================================================
// Pass A: coarse bucket scatter.  Block = CHUNK contiguous edges.
// LDS hist over NB buckets -> ONE global atomic per (block,bucket) reserves a
// contiguous run -> edges written via LDS cursors.  Per-block write window
// ~CHUNK*8B spread over ~NB short runs => L2-resident => full-line writebacks.
// Entry: val_bf16(16) << 48 | col(17) << 17 | row(17).
// ===========================================================================
__global__ __launch_bounds__(256) void bucket_scatter(
        const int* __restrict__ edge_row, const int* __restrict__ edge_col,
        const float* __restrict__ edge_val, int* __restrict__ bucket_cursor,
        unsigned long long* __restrict__ ebuck, int E, int NB) {
    __shared__ int cur[1024];  // hist, then per-bucket global cursor
    const int tid = threadIdx.x;
    const int e0  = blockIdx.x * CHUNK;
    const int e1  = min(e0 + CHUNK, E);

    for (int i = tid; i < 1024; i += 256) cur[i] = 0;
    __syncthreads();

    // phase 1: LDS histogram of this chunk
    for (int e = e0 + tid; e < e1; e += 256)
        atomicAdd(&cur[edge_row[e] >> BSHIFT], 1);
    __syncthreads();

    // phase 2: reserve a global run per non-empty bucket; cur becomes cursor
    for (int b = tid; b < NB; b += 256) {
        const int c = cur[b];
        cur[b] = (c > 0) ? atomicAdd(&bucket_cursor[b], c) : 0;
    }
    __syncthreads();

    // phase 3: write edges to their run
    for (int e = e0 + tid; e < e1; e += 256) {
        const int r = edge_row[e];
        const int b = r >> BSHIFT;
        const int pos = atomicAdd(&cur[b], 1);
        const unsigned long long pk =
            ((unsigned long long)(uint)f2bf_rne(edge_val[e]) << 48) |
            ((unsigned long long)(uint)edge_col[e] << 17) | (uint)r;
        ebuck[pos] = pk;
    }
}

// packed (col, val): low 32 = col, high 32 = val bits
__device__ inline long long pack_cv(int c, float v) {
    return (long long)(((unsigned long long)__builtin_bit_cast(uint, v) << 32) |
                       (uint)c);
}

// ===========================================================================
// Pass B: fine scatter within one bucket per block.  LDS cursors (no global
// atomics); epair target window ~32KB => L2-resident => full-line writebacks.
// Result: epair row-sorted, identical layout to the old fill_csr output.
// ===========================================================================
__global__ __launch_bounds__(256) void fine_scatter(
        const unsigned long long* __restrict__ ebuck,
        const int* __restrict__ row_start,
        long long* __restrict__ epair, int N, int E) {
    __shared__ int cur[BROWS];
    const int tid = threadIdx.x;
    const int r0  = blockIdx.x << BSHIFT;

    if (tid < BROWS) {
        const int r = r0 + tid;
        cur[tid] = (r < N) ? row_start[r] : E;  // rows >= N have no edges
    }
    __syncthreads();

    const int s = row_start[r0 < N ? r0 : N];
    const int rend = r0 + BROWS;
    const int e = row_start[rend < N ? rend : N];

    for (int i = s + tid; i < e; i += 256) {
        const unsigned long long pk = ebuck[i];
        const int  r  = (int)(pk & 0x1FFFFu);
        const int  c  = (int)((pk >> 17) & 0x1FFFFu);
        const uint vb = (uint)(pk >> 48);
        const float v = __builtin_bit_cast(float, vb << 16);
        const int pos = atomicAdd(&cur[r - r0], 1);
        epair[pos] = pack_cv(c, v);
    }
}

// ===========================================================================
// accumulate: one wave per row; 8 gathers in flight; bias folded in.
// (unchanged from round 4 — proven)
// ===========================================================================
__global__ __launch_bounds__(256) void accumulate(const ushort* __restrict__ sup,
                                                  const int* __restrict__ row_start,
                                                  const long long* __restrict__ epair,
                                                  const float* __restrict__ bias,
                                                  float* __restrict__ out, int N) {
    const int row = blockIdx.x * 4 + (threadIdx.x >> 6);
    if (row >= N) return;
    const int lane = threadIdx.x & 63;
    const int lofs = lane * 4;  // ushort offset within a sup row

    const int s = row_start[row];
    const int e = row_start[row + 1];

    f32x4 a[8];
    a[0] = *(const f32x4*)(bias + lofs);
#pragma unroll
    for (int q = 1; q < 8; ++q) a[q] = (f32x4){0.f, 0.f, 0.f, 0.f};

    for (int base = s; base < e; base += 64) {
        const int idx = base + lane;
        long long pk = 0;
        if (idx < e) pk = __builtin_nontemporal_load(epair + idx);
        const int   c = (int)(uint)pk;
        const float v = __builtin_bit_cast(float, (uint)((unsigned long long)pk >> 32));
        const int n = min(64, e - base);
        int j = 0;
        for (; j + 7 < n; j += 8) {
            int   cq[8];
            float vq[8];
            uint2 uq[8];
#pragma unroll
            for (int q = 0; q < 8; ++q) {
                cq[q] = __shfl(c, j + q);
                vq[q] = __shfl(v, j + q);
            }
#pragma unroll
            for (int q = 0; q < 8; ++q)
                uq[q] = *(const uint2*)(sup + ((uint)cq[q] << 8) + lofs);
#pragma unroll
            for (int q = 0; q < 8; ++q) {
                const float f0 = __builtin_bit_cast(float, uq[q].x << 16);
                const float f1 = __builtin_bit_cast(float, uq[q].x & 0xFFFF0000u);
                const float f2 = __builtin_bit_cast(float, uq[q].y << 16);
                const float f3 = __builtin_bit_cast(float, uq[q].y & 0xFFFF0000u);
                a[q][0] = fmaf(vq[q], f0, a[q][0]);
                a[q][1] = fmaf(vq[q], f1, a[q][1]);
                a[q][2] = fmaf(vq[q], f2, a[q][2]);
                a[q][3] = fmaf(vq[q], f3, a[q][3]);
            }
        }
        for (; j < n; ++j) {
            const int   c0 = __shfl(c, j);
            const float v0 = __shfl(v, j);
            const uint2 u  = *(const uint2*)(sup + ((uint)c0 << 8) + lofs);
            const float f0 = __builtin_bit_cast(float, u.x << 16);
            const float f1 = __builtin_bit_cast(float, u.x & 0xFFFF0000u);
            const float f2 = __builtin_bit_cast(float, u.y << 16);
            const float f3 = __builtin_bit_cast(float, u.y & 0xFFFF0000u);
            a[0][0] = fmaf(v0, f0, a[0][0]);
            a[0][1] = fmaf(v0, f1, a[0][1]);
            a[0][2] = fmaf(v0, f2, a[0][2]);
            a[0][3] = fmaf(v0, f3, a[0][3]);
        }
    }
#pragma unroll
    for (int q = 1; q < 8; ++q) {
        a[0][0] += a[q][0]; a[0][1] += a[q][1];
        a[0][2] += a[q][2]; a[0][3] += a[q][3];
    }
    __builtin_nontemporal_store(a[0], (f32x4*)(out + (size_t)row * D + lofs));
}

// ===========================================================================
extern "C" void kernel_launch(void* const* d_in, const int* in_sizes, int n_in,
                              void* d_out, int out_size, void* d_ws, size_t ws_size,
                              hipStream_t stream) {
    const float* x        = (const float*)d_in[0];
    const float* edge_val = (const float*)d_in[1];
    const float* weight   = (const float*)d_in[2];
    const float* bias     = (const float*)d_in[3];
    const int*   edge_row = (const int*)d_in[4];
    const int*   edge_col = (const int*)d_in[5];
    float*       out      = (float*)d_out;

    const int N = in_sizes[0] / D;   // 100000
    const int E = in_sizes[1];       // 3200000

    char* ws = (char*)d_ws;
    size_t off = 0;
    auto carve = [&](size_t bytes) -> char* {
        char* p = ws + off;
        off = (off + bytes + 255) & ~(size_t)255;
        return p;
    };

    const int nblk = (N + 255) / 256;          // 391
    const int NB   = (N + BROWS - 1) / BROWS;  // 782 coarse buckets

    ushort*    sup       = (ushort*)carve((size_t)N * D * sizeof(ushort));   // 51.2 MB
    ushort*    wt        = (ushort*)carve((size_t)D * D * sizeof(ushort));   // 128 KB
    int*       row_start = (int*)carve((size_t)(N + 1) * sizeof(int));
    int*       cnt       = (int*)carve((size_t)N * sizeof(int));
    long long* epair     = (long long*)carve((size_t)E * sizeof(long long)); // 25.6 MB
    unsigned long long* ebuck =
        (unsigned long long*)carve((size_t)E * sizeof(unsigned long long));  // 25.6 MB
    int*       bcursor   = (int*)carve((size_t)NB * sizeof(int));
    int*       partial   = (int*)carve((size_t)nblk * sizeof(int));

    // 1) W -> wt (bf16 transposed), support = bf16(x @ W)
    conv_wt<<<(D * D) / 256, 256, 0, stream>>>(weight, wt);
    gemm_mfma<<<(N + 63) / 64, 256, 0, stream>>>(x, wt, sup, N);

    // 2) fine histogram + scan -> row_start
    zero_ints<<<nblk, 256, 0, stream>>>(cnt, N);
    hist_rows<<<(E / 4 + 255) / 256, 256, 0, stream>>>(edge_row, cnt, E);
    scan_local<<<nblk, 256, 0, stream>>>(cnt, row_start, partial, N);
    scan_partials<<<1, 512, 0, stream>>>(partial, nblk);
    scan_finalize<<<nblk, 256, 0, stream>>>(row_start, partial, N, E);

    // 3) two-level scatter: coarse buckets, then row-sorted epair
    init_bcursor<<<(NB + 255) / 256, 256, 0, stream>>>(row_start, bcursor, N, NB);
    bucket_scatter<<<(E + CHUNK - 1) / CHUNK, 256, 0, stream>>>(
        edge_row, edge_col, edge_val, bcursor, ebuck, E, NB);
    fine_scatter<<<NB, 256, 0, stream>>>(ebuck, row_start, epair, N, E);

    // 4) gather-accumulate (bias folded in)
    accumulate<<<(N + 3) / 4, 256, 0, stream>>>(sup, row_start, epair, bias, out, N);
}